// Round 1
// baseline (3760.473 us; speedup 1.0000x reference)
//
#include <hip/hip_runtime.h>
#include <hip/hip_fp16.h>

#define T_SZ 365
#define IN_SZ 32
#define H_SZ 256
#define G4 1024
#define K_SZ 288
#define M_BLK 32          // batch rows per group (pair of blocks)
#define NGRP 128          // groups: 128 * 32 = 4096 rows
#define NTHR 512          // 8 waves, each owns a distinct 16-col W slice
#define NBLK 256          // 1 block per CU, all co-resident
#define XP 40             // x_s padded row stride in halfs (80 B)
#define HROWB 512         // bytes per hs row (256 halfs, dense + XOR swizzle)
#define HS_BYTES (M_BLK * HROWB)   // 16384 B per h image

// workspace offsets (bytes)
#define ARR_OFF (640*1024)
#define HX_OFF  (1024*1024)

typedef _Float16 f16x8 __attribute__((ext_vector_type(8)));
typedef _Float16 f16x2 __attribute__((ext_vector_type(2)));
typedef float f32x4 __attribute__((ext_vector_type(4)));
typedef unsigned long long u64;

__device__ __forceinline__ float fast_sigmoid(float x) {
    float e = __builtin_amdgcn_exp2f(-1.4426950408889634f * x);
    return __builtin_amdgcn_rcpf(1.0f + e);
}
__device__ __forceinline__ float fast_tanh(float x) {
    float e = __builtin_amdgcn_exp2f(2.8853900817779268f * x);
    return 1.0f - 2.0f * __builtin_amdgcn_rcpf(1.0f + e);
}

// Pack W = [w_hh | w_ih] as fp16, layout [gate-row][k] (k contiguous) = B^T.
__global__ void pack_w_kernel(const float* __restrict__ w_ih,
                              const float* __restrict__ w_hh,
                              _Float16* __restrict__ wp) {
    int idx = blockIdx.x * 256 + threadIdx.x;
    if (idx >= G4 * K_SZ) return;
    int g = idx / K_SZ, k = idx - g * K_SZ;
    float v = (k < H_SZ) ? w_hh[g * H_SZ + k] : w_ih[g * IN_SZ + (k - H_SZ)];
    wp[idx] = (_Float16)v;
}

__global__ void init_sync_kernel(unsigned int* arrive) {
    for (int i = threadIdx.x; i < NGRP * 16; i += 256) arrive[i] = 0u;
}

__global__ __launch_bounds__(NTHR, 2) void lstm_kernel(
    const float* __restrict__ xd, const float* __restrict__ b,
    const _Float16* __restrict__ wp, const float* __restrict__ w_out,
    const float* __restrict__ b_out, float* __restrict__ out,
    u64* hx, unsigned int* arrive)
{
    // h double-buffer: dense 512-B rows, XOR-swizzled (byte ^= (row&7)<<4 on bits 4..6)
    __shared__ __align__(16) _Float16 hs[2][M_BLK * 256];   // 2 x 16 KB
    __shared__ __align__(16) _Float16 x_s[M_BLK * XP];      // 2.5 KB, +pad vs conflicts

    const int tid  = threadIdx.x;
    const int wq   = tid >> 6;        // wave 0..7: owns cols [q*128 + wq*16, +16)
    const int lane = tid & 63;
    const int quad = lane >> 4;
    const int l16  = lane & 15;
    const int blk  = blockIdx.x;
    const int g    = blk & (NGRP - 1);   // pair (g, g+128) -> same XCD (%8 equal)
    const int q    = blk >> 7;           // member 0/1

    const int jcol = q * 128 + wq * 16 + l16;   // this lane's global h column

    // ---- W slice (4 gates x 16 j-cols x K=288) entirely in registers: 144 VGPR ----
    f16x8 wfr[4][9];
#pragma unroll
    for (int G = 0; G < 4; ++G) {
        const _Float16* wr = wp + (size_t)(G * 256 + jcol) * K_SZ + quad * 8;
#pragma unroll
        for (int kt = 0; kt < 9; ++kt)
            wfr[G][kt] = *(const f16x8*)(wr + kt * 32);
    }
    float bias[4];
#pragma unroll
    for (int G = 0; G < 4; ++G) bias[G] = b[G * 256 + jcol];

    // ---- loop-invariant swizzled A-read offsets: row l16 (a0), +16 rows (a1) ----
    const int swz = (l16 & 7) << 4;
    int a_off[8];
#pragma unroll
    for (int kt = 0; kt < 8; ++kt)
        a_off[kt] = l16 * HROWB + ((kt * 64 + quad * 16) ^ swz);
    const int x_off = l16 * (XP * 2) + quad * 16;   // x_s is padded, no swizzle

    // x loader: row = tid>>4 (32 rows), 2 consecutive floats per thread
    const int xr = tid >> 4;
    const int xe = tid & 15;
    const float* xrow = xd + (size_t)(g * M_BLK + xr) * (T_SZ * IN_SZ) + xe * 2;
    float2 xa = *(const float2*)xrow;

    // zero hs[0] (h_0 = 0): 32 B per thread
    {
        u64* z = (u64*)&hs[0][0];
#pragma unroll
        for (int i = 0; i < 4; ++i) z[tid * 4 + i] = 0ull;
    }
    // stage x_0
    *(f16x2*)((char*)x_s + xr * (XP * 2) + xe * 4) = (f16x2){(_Float16)xa.x, (_Float16)xa.y};

    f32x4 creg[2];
    creg[0] = (f32x4){0.f, 0.f, 0.f, 0.f};
    creg[1] = (f32x4){0.f, 0.f, 0.f, 0.f};

    __syncthreads();

    unsigned int* myf = &arrive[g * 16 + q];
    unsigned int* prf = &arrive[g * 16 + (1 - q)];
    unsigned int target = 0;
    const f32x4 vzero = {0.f, 0.f, 0.f, 0.f};

    // push: own 16 chunks/row (chunk bit4 = ownership, unaffected by swizzle XOR)
    const int push_b = (tid >> 4) * HROWB + (q * 16 + (tid & 15)) * 16;
    // pull: partner's 16 chunks/row only (own half already written locally)
    const int pull_b = (tid >> 4) * HROWB + ((1 - q) * 16 + (tid & 15)) * 16;

    int pb = 0;   // pb == t&1
    for (int t = 0; t < T_SZ; ++t) {
        const char* hsR = (const char*)&hs[pb][0];     // h_t
        char* hsW = (char*)&hs[pb ^ 1][0];             // h_{t+1}

        // ---- GEMM: preacts[32 x 128-slice] = A[32 x 288] @ Wslice^T (W in regs) ----
        f32x4 acc[2][4];
#pragma unroll
        for (int mt = 0; mt < 2; ++mt)
#pragma unroll
            for (int G = 0; G < 4; ++G) acc[mt][G] = vzero;

#pragma unroll
        for (int kt = 0; kt < 8; ++kt) {
            f16x8 a0 = *(const f16x8*)(hsR + a_off[kt]);
            f16x8 a1 = *(const f16x8*)(hsR + a_off[kt] + 16 * HROWB);
#pragma unroll
            for (int G = 0; G < 4; ++G) {
                acc[0][G] = __builtin_amdgcn_mfma_f32_16x16x32_f16(a0, wfr[G][kt], acc[0][G], 0, 0, 0);
                acc[1][G] = __builtin_amdgcn_mfma_f32_16x16x32_f16(a1, wfr[G][kt], acc[1][G], 0, 0, 0);
            }
        }
        {   // x part (k 256..287)
            f16x8 a0 = *(const f16x8*)((const char*)x_s + x_off);
            f16x8 a1 = *(const f16x8*)((const char*)x_s + x_off + 16 * (XP * 2));
#pragma unroll
            for (int G = 0; G < 4; ++G) {
                acc[0][G] = __builtin_amdgcn_mfma_f32_16x16x32_f16(a0, wfr[G][8], acc[0][G], 0, 0, 0);
                acc[1][G] = __builtin_amdgcn_mfma_f32_16x16x32_f16(a1, wfr[G][8], acc[1][G], 0, 0, 0);
            }
        }

        // prefetch next x
        if (t + 1 < T_SZ)
            xa = *(const float2*)(xrow + (size_t)(t + 1) * IN_SZ);

        // ---- activations + state update; h_{t+1} -> own cols of hsW (swizzled) ----
#pragma unroll
        for (int mt = 0; mt < 2; ++mt) {
#pragma unroll
            for (int r = 0; r < 4; ++r) {
                float iv = fast_sigmoid(acc[mt][0][r] + bias[0]);
                float fv = fast_sigmoid(acc[mt][1][r] + bias[1]);
                float gv = fast_tanh  (acc[mt][2][r] + bias[2]);
                float ov = fast_sigmoid(acc[mt][3][r] + bias[3]);
                float cv = fv * creg[mt][r] + iv * gv;
                creg[mt][r] = cv;
                float hv = ov * fast_tanh(cv);
                int m = mt * 16 + quad * 4 + r;
                *(_Float16*)(hsW + m * HROWB + ((jcol * 2) ^ ((m & 7) << 4))) = (_Float16)hv;
            }
        }
        __syncthreads();   // S1: own h half complete in hsW

        // ---- push own half (8 KB): one coalesced 16-B chunk per thread ----
        u64* hxg = hx + ((size_t)pb * NGRP + g) * (HS_BYTES / 8);
        {
            f16x8 v = *(const f16x8*)(hsW + push_b);
            u64 lo = ((const u64*)&v)[0];
            u64 hi = ((const u64*)&v)[1];
            __hip_atomic_store(&hxg[push_b / 8],     lo, __ATOMIC_RELAXED, __HIP_MEMORY_SCOPE_AGENT);
            __hip_atomic_store(&hxg[push_b / 8 + 1], hi, __ATOMIC_RELAXED, __HIP_MEMORY_SCOPE_AGENT);
        }
        // stage x_{t+1} under the store drain
        if (t + 1 < T_SZ)
            *(f16x2*)((char*)x_s + xr * (XP * 2) + xe * 4) = (f16x2){(_Float16)xa.x, (_Float16)xa.y};

        asm volatile("s_waitcnt vmcnt(0)" ::: "memory");
        __syncthreads();   // S2: every wave's pushes drained

        // ---- 2-party barrier: symmetric flag store + poll (no RMW) ----
        target += 1;
        if (tid == 0) {
            __hip_atomic_store(myf, target, __ATOMIC_RELEASE, __HIP_MEMORY_SCOPE_AGENT);
            while (__hip_atomic_load(prf, __ATOMIC_ACQUIRE, __HIP_MEMORY_SCOPE_AGENT) < target)
                __builtin_amdgcn_s_sleep(1);
        }
        __syncthreads();   // S3

        // ---- pull partner half (8 KB): 16 B per thread, linear copy ----
        {
            u64 w0 = __hip_atomic_load(&hxg[pull_b / 8],     __ATOMIC_RELAXED, __HIP_MEMORY_SCOPE_AGENT);
            u64 w1 = __hip_atomic_load(&hxg[pull_b / 8 + 1], __ATOMIC_RELAXED, __HIP_MEMORY_SCOPE_AGENT);
            *(u64*)(hsW + pull_b)     = w0;
            *(u64*)(hsW + pull_b + 8) = w1;
        }
        __syncthreads();   // S4: hsW = full h_{t+1}
        pb ^= 1;
    }

    // ---- epilogue: out[m] = relu(h_T . w_out + b_out); member q==0 writes ----
    if (q == 0) {
        const char* hsF = (const char*)&hs[pb][0];
        const int m = tid >> 4, p = tid & 15;
        const int swzm = (m & 7) << 4;
        float s = 0.f;
#pragma unroll
        for (int jj = 0; jj < 16; ++jj) {
            int j = p * 16 + jj;
            s += (float)*(const _Float16*)(hsF + m * HROWB + ((j * 2) ^ swzm)) * w_out[j];
        }
        s += __shfl_xor(s, 1);
        s += __shfl_xor(s, 2);
        s += __shfl_xor(s, 4);
        s += __shfl_xor(s, 8);
        if (p == 0) out[(size_t)g * M_BLK + m] = fmaxf(s + b_out[0], 0.f);
    }
}

extern "C" void kernel_launch(void* const* d_in, const int* in_sizes, int n_in,
                              void* d_out, int out_size, void* d_ws, size_t ws_size,
                              hipStream_t stream) {
    const float* xd    = (const float*)d_in[0];
    const float* w_ih  = (const float*)d_in[1];
    const float* w_hh  = (const float*)d_in[2];
    const float* b     = (const float*)d_in[3];
    const float* w_out = (const float*)d_in[4];
    const float* b_out = (const float*)d_in[5];
    float* out = (float*)d_out;

    _Float16* wp = (_Float16*)d_ws;                                 // 576 KB @ 0
    unsigned int* arrive = (unsigned int*)((char*)d_ws + ARR_OFF);  // 8 KB
    u64* hx = (u64*)((char*)d_ws + HX_OFF);                         // 4 MB (double-buffered)

    pack_w_kernel<<<(G4 * K_SZ + 255) / 256, 256, 0, stream>>>(w_ih, w_hh, wp);
    init_sync_kernel<<<1, 256, 0, stream>>>(arrive);
    lstm_kernel<<<NBLK, NTHR, 0, stream>>>(xd, b, wp, w_out, b_out, out, hx, arrive);
}